// Round 6
// baseline (1759.534 us; speedup 1.0000x reference)
//
#include <hip/hip_runtime.h>
#include <math.h>

// B=8, W=H=128, D=64, bs=4 -> M=N=8192 rows, F=1024 features.
// R12 = R11 with LDS cut 80->64 KB for 2-blocks/CU residency.
// Post-mortem R11: VALUBusy 60->25 (epilogue fixed) but MfmaUtil stuck at
// 28% with Occupancy 22.6% ~= ONE 8-wave block/CU (80KB LDS x2 = full
// 160KB pool doesn't co-schedule). Single block => ds_read and MFMA
// phases serialize at the two barriers (1240 MFMA cyc / ~4400 iter cyc
// = 28%). Fix: alias epilogue sK/sE (16KB) into As/Bs (only live after
// the K-loop; extra __syncthreads() after final vmcnt(0) orders LDS-DMA
// before reuse) -> 64KB LDS, launch_bounds(512,4) = 2 blocks/CU, so one
// block's staging/ds_read overlaps the other's MFMA cluster (T3 pays
// cross-block). LDS BW check: 2 blocks x ~880 cyc/iter reads < 2 x 1240
// cyc MFMA -> not BW-blocked. Main loop sync structure unchanged from
// R11 (counted vmcnt(4), raw s_barrier, both-sides slot swizzle).

#define NROWS 8192
#define KY 1024
#define NCH 32     // col partial chunks (one per 256-col tile)
#define EPS 3e-4f
#define FEPS 8e-4f   // >= EPS + worst key-quantization step (2^-11 at |v|<1)

typedef _Float16 v8h __attribute__((ext_vector_type(8)));
typedef float f32x4 __attribute__((ext_vector_type(4)));

__device__ __forceinline__ void gload16(const _Float16* g, _Float16* l) {
    __builtin_amdgcn_global_load_lds(
        (const __attribute__((address_space(1))) void*)g,
        (__attribute__((address_space(3))) void*)l, 16, 0, 0);
}

__device__ __forceinline__ unsigned umax(unsigned a, unsigned b) { return a > b ? a : b; }
__device__ __forceinline__ unsigned umin(unsigned a, unsigned b) { return a < b ? a : b; }

// monotone fp32->u32 map, truncate to 19 value bits, pack 13-bit (8191-col).
// Larger key == larger value; ties -> smaller col. Branchless.
__device__ __forceinline__ unsigned packKey(float v, int col) {
    unsigned b = __float_as_uint(v);
    b ^= (unsigned)((int)b >> 31) | 0x80000000u;
    return (b & 0xFFFFE000u) | (unsigned)(8191 - col);
}

// lower-bound float from a packed key (undo monotone map, low bits floored)
__device__ __forceinline__ float unpackApprox(unsigned k) {
    unsigned kb = k & 0xFFFFE000u;
    unsigned b = (kb & 0x80000000u) ? (kb ^ 0x80000000u) : ~kb;
    return __uint_as_float(b);
}

// merge two sorted-descending triples -> sorted top-3 of union (8 min/max)
#define KMERGE(a1, a2, a3, b1, b2, b3) do {                                 \
    unsigned _n1 = umax(a1, b1);                                            \
    unsigned _n2 = umax(umin(a1, b1), umax(a2, b2));                        \
    unsigned _n3 = umax(umax(a3, b3), umax(umin(a1, b2), umin(a2, b1)));    \
    a1 = _n1; a2 = _n2; a3 = _n3;                                           \
} while (0)

// One 64-lane wave per feature-row; 16 floats/lane; shuffle-only reductions.
__global__ __launch_bounds__(256) void normSplitKernel(
    const float* __restrict__ x, const float* __restrict__ y,
    _Float16* __restrict__ Xh, _Float16* __restrict__ Xl,
    _Float16* __restrict__ Yh, _Float16* __restrict__ Yl,
    int* __restrict__ flagCnt) {
    if (blockIdx.x == 0 && threadIdx.x == 0) *flagCnt = 0;
    int gr = blockIdx.x * 4 + (threadIdx.x >> 6);   // 0..16383
    int ln = threadIdx.x & 63;
    bool isX = gr < NROWS;
    int row = isX ? gr : gr - NROWS;
    const float* src = isX ? x : y;
    _Float16* dh = isX ? Xh : Yh;
    _Float16* dl = isX ? Xl : Yl;
    int b = row >> 10, wq = (row >> 5) & 31, hq = row & 31;
    int a = ln >> 4, c = (ln >> 2) & 3, d0 = (ln & 3) << 4;
    const float* p = &src[(((size_t)(b * 128) + wq * 4 + a) * 128 + hq * 4 + c) * 64 + d0];
    float vv[16];
    *(float4*)(vv + 0)  = *(const float4*)(p + 0);
    *(float4*)(vv + 4)  = *(const float4*)(p + 4);
    *(float4*)(vv + 8)  = *(const float4*)(p + 8);
    *(float4*)(vv + 12) = *(const float4*)(p + 12);
    double s = 0.0;
    #pragma unroll
    for (int q = 0; q < 16; q++) s += (double)vv[q];
    #pragma unroll
    for (int m = 1; m < 64; m <<= 1) s += __shfl_xor(s, m, 64);
    double mean = s * (1.0 / 1024.0);
    double ss = 0.0;
    #pragma unroll
    for (int q = 0; q < 16; q++) {
        double d = (double)vv[q] - mean;
        ss += d * d;
    }
    #pragma unroll
    for (int m = 1; m < 64; m <<= 1) ss += __shfl_xor(ss, m, 64);
    double scale = 1.0 / (sqrt(ss) + 1e-5);
    _Float16 hi[16], lo[16];
    #pragma unroll
    for (int q = 0; q < 16; q++) {
        float f = (float)(((double)vv[q] - mean) * scale);
        _Float16 h = (_Float16)f;
        hi[q] = h;
        lo[q] = (_Float16)(f - (float)h);
    }
    size_t f0 = (size_t)row * KY + (ln << 4);
    *(v8h*)&dh[f0]     = *(v8h*)(hi);
    *(v8h*)&dh[f0 + 8] = *(v8h*)(hi + 8);
    *(v8h*)&dl[f0]     = *(v8h*)(lo);
    *(v8h*)&dl[f0 + 8] = *(v8h*)(lo + 8);
}

// MFMA GEMM C = Xh * Yh^T (K=1024) fused per-row packed-key top-3.
// 256x256 tile, 8 waves 2x4, 128x64 per wave (8x4 frags of 16x16x32 f16).
__global__ __launch_bounds__(512, 4) void simKernel(
    const _Float16* __restrict__ Xh, const _Float16* __restrict__ Yh,
    float* __restrict__ pV1, unsigned* __restrict__ pK1,
    unsigned* __restrict__ pK2, unsigned* __restrict__ pK3) {
    __shared__ __align__(16) _Float16 As[2][256 * 32];   // 32 KB
    __shared__ __align__(16) _Float16 Bs[2][256 * 32];   // 32 KB -> 64 KB total
    const int t = threadIdx.x;
    const int l = t & 63, w = t >> 6;        // 8 waves
    const int wr = w >> 2, wc = w & 3;       // 2 x 4 wave grid
    const int quad = l >> 4, lm = l & 15;
    // grid transpose: consecutive flat ids share the A row-tile
    const int flat = blockIdx.x;
    const int bx = flat >> 5, by = flat & 31;
    const int r0 = bx * 256, c0 = by * 256;

    f32x4 acc[8][4];
    #pragma unroll
    for (int i = 0; i < 8; i++)
        #pragma unroll
        for (int j = 0; j < 4; j++) acc[i][j] = (f32x4){0.f, 0.f, 0.f, 0.f};

    // --- staging geometry (global_load_lds, linear LDS dest) ---
    // chunk c = q*512 + w*64 + l covers LDS halves [c*8, c*8+8) i.e. physical
    // row = c>>2, slot = c&3 of the row-major [256][32]-half tile.
    // Swizzle (both-sides): physical slot p stores logical slot p^(row&3),
    // so the per-lane GLOBAL source k-slot is pre-swizzled; ds_read applies
    // the same XOR. row&3 == (l>>2)&3 for all q,w.
    const int cq = l >> 2;                          // row within (q,w) group
    const int sA = (((l & 3) ^ (cq & 3)) << 3);     // swizzled src k-offset (halves)
    const _Float16* gA = Xh + (size_t)(r0 + w * 16 + cq) * KY + sA;
    const _Float16* gB = Yh + (size_t)(c0 + w * 16 + cq) * KY + sA;
    const int ldsBase = w * 512;                    // halves; +q*4096 per call

#define STAGE(bb, kt) do {                                             \
    const int _ko = (kt) * 32;                                         \
    gload16(gA + _ko,                     &As[bb][ldsBase]);           \
    gload16(gA + _ko + (size_t)128 * KY,  &As[bb][ldsBase + 4096]);    \
    gload16(gB + _ko,                     &Bs[bb][ldsBase]);           \
    gload16(gB + _ko + (size_t)128 * KY,  &Bs[bb][ldsBase + 4096]);    \
} while (0)

    // frag read offsets (halves), swizzled: row*32 + 8*(quad ^ (row&3)),
    // row&3 == lm&3 (row bases are multiples of 16)
    const int swz = (quad ^ (lm & 3)) << 3;
    const int offA0 = (wr * 128 + lm) * 32 + swz;   // + i*512
    const int offB0 = (wc * 64 + lm) * 32 + swz;    // + j*512

    // prologue: stage tiles 0,1; wait tile 0 only (tile 1 stays in flight)
    STAGE(0, 0);
    STAGE(1, 1);
    asm volatile("s_waitcnt vmcnt(4)" ::: "memory");
    __builtin_amdgcn_s_barrier();

    #pragma unroll 2
    for (int kt = 0; kt < 32; kt++) {
        const int cur = kt & 1;
        // 1. read this tile's fragments (12x ds_read_b128)
        v8h af[8], bf[4];
        #pragma unroll
        for (int i = 0; i < 8; i++) af[i] = *(const v8h*)&As[cur][offA0 + i * 512];
        #pragma unroll
        for (int j = 0; j < 4; j++) bf[j] = *(const v8h*)&Bs[cur][offB0 + j * 512];
        // 2. reads complete before anyone re-stages buf[cur]
        asm volatile("s_waitcnt lgkmcnt(0)" ::: "memory");
        __builtin_amdgcn_sched_barrier(0);
        __builtin_amdgcn_s_barrier();
        // 3. re-stage buf[cur] with tile kt+2 (wraps harmlessly at the tail)
        STAGE(cur, (kt + 2) & 31);
        // 4. MFMA cluster on registers
        __builtin_amdgcn_s_setprio(1);
        #pragma unroll
        for (int j = 0; j < 4; j++)
            #pragma unroll
            for (int i = 0; i < 8; i++)
                acc[i][j] = __builtin_amdgcn_mfma_f32_16x16x32_f16(af[i], bf[j], acc[i][j], 0, 0, 0);
        __builtin_amdgcn_s_setprio(0);
        // 5. tile kt+1 landed (mine); barrier makes it landed for everyone
        asm volatile("s_waitcnt vmcnt(4)" ::: "memory");
        __builtin_amdgcn_s_barrier();
    }
    asm volatile("s_waitcnt vmcnt(0)" ::: "memory");
    __syncthreads();   // all waves' LDS-DMA drained -> As/Bs reusable

    // Epilogue scratch aliased into the (dead) staging buffers:
    // sK = 12 KB at As[0], sE = 4 KB at Bs[0].
    unsigned (*sK)[4][128][3] = reinterpret_cast<unsigned (*)[4][128][3]>(&As[0][0]);
    float (*sE)[4][128]       = reinterpret_cast<float (*)[4][128]>(&Bs[0][0]);
#undef STAGE

    // Epilogue: packed-key top-3 per row over this wave's 64 cols.
    // C frag layout: col=lane&15, row=quad*4+reg.
    const int cbase = c0 + wc * 64 + lm;
    #pragma unroll
    for (int i = 0; i < 8; i++) {
        #pragma unroll
        for (int r = 0; r < 4; r++) {
            float v0 = acc[i][0][r], v1 = acc[i][1][r];
            float v2 = acc[i][2][r], v3 = acc[i][3][r];
            unsigned k0 = packKey(v0, cbase);
            unsigned k1 = packKey(v1, cbase + 16);
            unsigned k2 = packKey(v2, cbase + 32);
            unsigned k3 = packKey(v3, cbase + 48);
            // local sorted top-3 of 4 (two sorted pairs -> order stats)
            unsigned h1 = umax(k0, k1), l1 = umin(k0, k1);
            unsigned h2 = umax(k2, k3), l2 = umin(k2, k3);
            unsigned a1 = umax(h1, h2);
            unsigned a2 = umax(umin(h1, h2), umax(l1, l2));
            unsigned a3 = umax(umin(h1, l2), umin(l1, h2));
            float ev = fmaxf(fmaxf(v0, v1), fmaxf(v2, v3));
            #pragma unroll
            for (int m = 1; m < 16; m <<= 1) {
                unsigned b1 = (unsigned)__shfl_xor((int)a1, m, 64);
                unsigned b2 = (unsigned)__shfl_xor((int)a2, m, 64);
                unsigned b3 = (unsigned)__shfl_xor((int)a3, m, 64);
                float be = __shfl_xor(ev, m, 64);
                KMERGE(a1, a2, a3, b1, b2, b3);
                ev = fmaxf(ev, be);
            }
            if (lm == 0) {
                int rr = i * 16 + quad * 4 + r;   // 0..127 within wave rows
                sK[wr][wc][rr][0] = a1; sK[wr][wc][rr][1] = a2; sK[wr][wc][rr][2] = a3;
                sE[wr][wc][rr] = ev;
            }
        }
    }
    __syncthreads();
    // merge 4 wave-columns; threads 0..255 each own one of the 256 rows
    if (t < 256) {
        const int mwr = t >> 7, ri = t & 127;
        unsigned a1 = sK[mwr][0][ri][0], a2 = sK[mwr][0][ri][1], a3 = sK[mwr][0][ri][2];
        float ev = sE[mwr][0][ri];
        #pragma unroll
        for (int q = 1; q < 4; q++) {
            unsigned b1 = sK[mwr][q][ri][0], b2 = sK[mwr][q][ri][1], b3 = sK[mwr][q][ri][2];
            KMERGE(a1, a2, a3, b1, b2, b3);
            ev = fmaxf(ev, sE[mwr][q][ri]);
        }
        size_t o = (size_t)by * NROWS + (r0 + t);
        pV1[o] = ev;
        pK1[o] = a1; pK2[o] = a2; pK3[o] = a3;
    }
}

// 128 blocks, 4 threads per row, 8 chunks each; shuffle-merge across sub.
__global__ __launch_bounds__(256) void reduceKernel(
    const float* __restrict__ pV1, const unsigned* __restrict__ pK1,
    const unsigned* __restrict__ pK2, const unsigned* __restrict__ pK3,
    int* __restrict__ bestIdx, int* __restrict__ flagRows,
    int* __restrict__ flagC2, int* __restrict__ flagC3,
    int* __restrict__ flagCnt, float* __restrict__ blkSum) {
    int t = threadIdx.x;
    int g = blockIdx.x * 256 + t;
    int row = g >> 2, sub = g & 3;
    unsigned a1 = 0, a2 = 0, a3 = 0;
    float ev = -1e30f;
    #pragma unroll
    for (int k = 0; k < 8; k++) {
        size_t o = (size_t)(sub + (k << 2)) * NROWS + row;
        unsigned b1 = pK1[o], b2 = pK2[o], b3 = pK3[o];
        float e = pV1[o];
        KMERGE(a1, a2, a3, b1, b2, b3);
        ev = fmaxf(ev, e);
    }
    #pragma unroll
    for (int m = 1; m < 4; m <<= 1) {
        unsigned b1 = (unsigned)__shfl_xor((int)a1, m, 64);
        unsigned b2 = (unsigned)__shfl_xor((int)a2, m, 64);
        unsigned b3 = (unsigned)__shfl_xor((int)a3, m, 64);
        float be = __shfl_xor(ev, m, 64);
        KMERGE(a1, a2, a3, b1, b2, b3);
        ev = fmaxf(ev, be);
    }
    bool lead = (t & 3) == 0;
    if (lead) {
        bestIdx[row] = 8191 - (int)(a1 & 8191u);
        // flag if exact max minus lower-bound of 2nd key is within margin
        if (ev - unpackApprox(a2) < FEPS) {
            int s = atomicAdd(flagCnt, 1);
            flagRows[s] = row;
            flagC2[s] = 8191 - (int)(a2 & 8191u);
            flagC3[s] = 8191 - (int)(a3 & 8191u);
        }
    }
    double sum = lead ? 1.0 - (double)ev : 0.0;
    __shared__ double sh[4];
    #pragma unroll
    for (int off = 32; off; off >>= 1) sum += __shfl_down(sum, off, 64);
    if ((t & 63) == 0) sh[t >> 6] = sum;
    __syncthreads();
    if (t == 0) blkSum[blockIdx.x] = (float)(sh[0] + sh[1] + sh[2] + sh[3]);
}

// Exact fp64 re-check of top-3 candidates for near-tie rows; one wave per row.
__global__ __launch_bounds__(256) void refineKernel(
    const _Float16* __restrict__ Xh, const _Float16* __restrict__ Xl,
    const _Float16* __restrict__ Yh, const _Float16* __restrict__ Yl,
    int* __restrict__ bestIdx, const int* __restrict__ flagRows,
    const int* __restrict__ flagC2, const int* __restrict__ flagC3,
    const int* __restrict__ flagCnt) {
    int n = *flagCnt;
    int wave = (blockIdx.x << 2) + (threadIdx.x >> 6);
    int ln = threadIdx.x & 63;
    for (int fi = wave; fi < n; fi += gridDim.x * 4) {
        int row = flagRows[fi];
        int cand[3];
        cand[0] = bestIdx[row]; cand[1] = flagC2[fi]; cand[2] = flagC3[fi];
        double d[3];
        #pragma unroll
        for (int c = 0; c < 3; c++) {
            double p = 0.0;
            int yr = cand[c];
            #pragma unroll
            for (int q = 0; q < 16; q++) {
                int k = (ln << 4) + q;
                float xv = (float)Xh[(size_t)row * KY + k] + (float)Xl[(size_t)row * KY + k];
                float yv = (float)Yh[(size_t)yr * KY + k] + (float)Yl[(size_t)yr * KY + k];
                p += (double)xv * yv;
            }
            #pragma unroll
            for (int m = 1; m < 64; m <<= 1) p += __shfl_xor(p, m, 64);
            d[c] = p;
        }
        if (ln == 0) {
            int bi = cand[0]; double bv = d[0];
            #pragma unroll
            for (int c = 1; c < 3; c++) {
                if (d[c] > bv || (d[c] == bv && cand[c] < bi)) { bv = d[c]; bi = cand[c]; }
            }
            bestIdx[row] = bi;
        }
    }
}

// new_x gather (hi+lo reconstruct ~ fp32 codebook) + loss finalize.
__global__ __launch_bounds__(256) void gatherKernel(
    const _Float16* __restrict__ Yh, const _Float16* __restrict__ Yl,
    const int* __restrict__ bestIdx, const float* __restrict__ blkSum,
    float* __restrict__ out) {
    int t = threadIdx.x;
    if (blockIdx.x == 0 && t == 0) {
        double s = 0.0;
        for (int i = 0; i < 128; i++) s += (double)blkSum[i];
        out[0] = (float)(s / 8192.0);
    }
    int g = (blockIdx.x * 256 + t) << 2;
    int b = g >> 20, wq = (g >> 13) & 127, hq = (g >> 6) & 127, d = g & 63;
    int row = (b << 10) + ((wq >> 2) << 5) + (hq >> 2);
    int f = ((wq & 3) << 8) + ((hq & 3) << 6) + d;
    size_t base = (size_t)bestIdx[row] * KY + f;
    const _Float16* ph = &Yh[base];
    const _Float16* pl = &Yl[base];
    out[1 + g + 0] = (float)ph[0] + (float)pl[0];
    out[1 + g + 1] = (float)ph[1] + (float)pl[1];
    out[1 + g + 2] = (float)ph[2] + (float)pl[2];
    out[1 + g + 3] = (float)ph[3] + (float)pl[3];
}

extern "C" void kernel_launch(void* const* d_in, const int* in_sizes, int n_in,
                              void* d_out, int out_size, void* d_ws, size_t ws_size,
                              hipStream_t stream) {
    const float* x = (const float*)d_in[0];
    const float* y = (const float*)d_in[1];
    float* out = (float*)d_out;
    char* ws = (char*)d_ws;
    _Float16* Xh  = (_Float16*)(ws);
    _Float16* Xl  = (_Float16*)(ws + 16777216u);
    _Float16* Yh  = (_Float16*)(ws + 33554432u);
    _Float16* Yl  = (_Float16*)(ws + 50331648u);
    float* pV1    = (float*)(ws + 67108864u);
    unsigned* pK1 = (unsigned*)(ws + 69206016u);
    unsigned* pK2 = (unsigned*)(ws + 71303168u);
    unsigned* pK3 = (unsigned*)(ws + 73400320u);
    int* bestIdx  = (int*)  (ws + 79691776u);
    int* flagRows = (int*)  (ws + 79724544u);
    int* flagC2   = (int*)  (ws + 79757312u);
    int* flagC3   = (int*)  (ws + 79790080u);
    int* flagCnt  = (int*)  (ws + 79822848u);
    float* blkSum = (float*)(ws + 79822976u);

    normSplitKernel<<<4096, 256, 0, stream>>>(x, y, Xh, Xl, Yh, Yl, flagCnt);
    simKernel<<<1024, 512, 0, stream>>>(Xh, Yh, pV1, pK1, pK2, pK3);
    reduceKernel<<<128, 256, 0, stream>>>(pV1, pK1, pK2, pK3,
                                          bestIdx, flagRows, flagC2, flagC3, flagCnt, blkSum);
    refineKernel<<<64, 256, 0, stream>>>(Xh, Xl, Yh, Yl, bestIdx,
                                         flagRows, flagC2, flagC3, flagCnt);
    gatherKernel<<<8192, 256, 0, stream>>>(Yh, Yl, bestIdx, blkSum, out);
}

// Round 7
// 320.743 us; speedup vs baseline: 5.4858x; 5.4858x over previous
//
#include <hip/hip_runtime.h>
#include <math.h>

// B=8, W=H=128, D=64, bs=4 -> M=N=8192 rows, F=1024 features.
// R13 = R11 main structure, BK 32->64, ONE barrier per K-tile.
// Post-mortem R12: launch_bounds(512,4) forced regs<=128 vs 128 AGPR acc
// + ~100 VGPR need -> accumulator spilled to scratch (FETCH 103MB->2.9GB,
// 63% HBM, sim 1637us). 2 blocks/CU is register-infeasible at 256^2 tile.
// R13 gets the read/MFMA overlap INTRA-block instead: per 64-K tile,
// {stage kt+1 (8 gload16, 1-ahead into buf^1) ; reads ks0 ; MFMA ks0 ;
// reads ks1 ; MFMA ks1 ; vmcnt(0) (issued ~2500cy earlier => free) ;
// s_barrier}. No barrier between read and MFMA phases -> 8 waves free-run,
// LDS pipe and MFMA pipe co-schedule (m114); barriers 65 -> 17 total.
// Swizzle: full 8-slot XOR (phys slot = logical ^ (row&7)), both sides:
// pre-swizzled global source (gload_lds dest stays linear) + swizzled
// ds_read cols -> 2-way max per quarter-wave (free, m136). LDS 144KB,
// 1 block/CU, launch_bounds(512,2): same register profile as R11 (no spill).

#define NROWS 8192
#define KY 1024
#define NCH 32     // col partial chunks (one per 256-col tile)
#define EPS 3e-4f
#define FEPS 8e-4f   // >= EPS + worst key-quantization step (2^-11 at |v|<1)

typedef _Float16 v8h __attribute__((ext_vector_type(8)));
typedef float f32x4 __attribute__((ext_vector_type(4)));

__device__ __forceinline__ void gload16(const _Float16* g, _Float16* l) {
    __builtin_amdgcn_global_load_lds(
        (const __attribute__((address_space(1))) void*)g,
        (__attribute__((address_space(3))) void*)l, 16, 0, 0);
}

__device__ __forceinline__ unsigned umax(unsigned a, unsigned b) { return a > b ? a : b; }
__device__ __forceinline__ unsigned umin(unsigned a, unsigned b) { return a < b ? a : b; }

// monotone fp32->u32 map, truncate to 19 value bits, pack 13-bit (8191-col).
// Larger key == larger value; ties -> smaller col. Branchless.
__device__ __forceinline__ unsigned packKey(float v, int col) {
    unsigned b = __float_as_uint(v);
    b ^= (unsigned)((int)b >> 31) | 0x80000000u;
    return (b & 0xFFFFE000u) | (unsigned)(8191 - col);
}

// lower-bound float from a packed key (undo monotone map, low bits floored)
__device__ __forceinline__ float unpackApprox(unsigned k) {
    unsigned kb = k & 0xFFFFE000u;
    unsigned b = (kb & 0x80000000u) ? (kb ^ 0x80000000u) : ~kb;
    return __uint_as_float(b);
}

// merge two sorted-descending triples -> sorted top-3 of union (8 min/max)
#define KMERGE(a1, a2, a3, b1, b2, b3) do {                                 \
    unsigned _n1 = umax(a1, b1);                                            \
    unsigned _n2 = umax(umin(a1, b1), umax(a2, b2));                        \
    unsigned _n3 = umax(umax(a3, b3), umax(umin(a1, b2), umin(a2, b1)));    \
    a1 = _n1; a2 = _n2; a3 = _n3;                                           \
} while (0)

// One 64-lane wave per feature-row; 16 floats/lane; shuffle-only reductions.
__global__ __launch_bounds__(256) void normSplitKernel(
    const float* __restrict__ x, const float* __restrict__ y,
    _Float16* __restrict__ Xh, _Float16* __restrict__ Xl,
    _Float16* __restrict__ Yh, _Float16* __restrict__ Yl,
    int* __restrict__ flagCnt) {
    if (blockIdx.x == 0 && threadIdx.x == 0) *flagCnt = 0;
    int gr = blockIdx.x * 4 + (threadIdx.x >> 6);   // 0..16383
    int ln = threadIdx.x & 63;
    bool isX = gr < NROWS;
    int row = isX ? gr : gr - NROWS;
    const float* src = isX ? x : y;
    _Float16* dh = isX ? Xh : Yh;
    _Float16* dl = isX ? Xl : Yl;
    int b = row >> 10, wq = (row >> 5) & 31, hq = row & 31;
    int a = ln >> 4, c = (ln >> 2) & 3, d0 = (ln & 3) << 4;
    const float* p = &src[(((size_t)(b * 128) + wq * 4 + a) * 128 + hq * 4 + c) * 64 + d0];
    float vv[16];
    *(float4*)(vv + 0)  = *(const float4*)(p + 0);
    *(float4*)(vv + 4)  = *(const float4*)(p + 4);
    *(float4*)(vv + 8)  = *(const float4*)(p + 8);
    *(float4*)(vv + 12) = *(const float4*)(p + 12);
    double s = 0.0;
    #pragma unroll
    for (int q = 0; q < 16; q++) s += (double)vv[q];
    #pragma unroll
    for (int m = 1; m < 64; m <<= 1) s += __shfl_xor(s, m, 64);
    double mean = s * (1.0 / 1024.0);
    double ss = 0.0;
    #pragma unroll
    for (int q = 0; q < 16; q++) {
        double d = (double)vv[q] - mean;
        ss += d * d;
    }
    #pragma unroll
    for (int m = 1; m < 64; m <<= 1) ss += __shfl_xor(ss, m, 64);
    double scale = 1.0 / (sqrt(ss) + 1e-5);
    _Float16 hi[16], lo[16];
    #pragma unroll
    for (int q = 0; q < 16; q++) {
        float f = (float)(((double)vv[q] - mean) * scale);
        _Float16 h = (_Float16)f;
        hi[q] = h;
        lo[q] = (_Float16)(f - (float)h);
    }
    size_t f0 = (size_t)row * KY + (ln << 4);
    *(v8h*)&dh[f0]     = *(v8h*)(hi);
    *(v8h*)&dh[f0 + 8] = *(v8h*)(hi + 8);
    *(v8h*)&dl[f0]     = *(v8h*)(lo);
    *(v8h*)&dl[f0 + 8] = *(v8h*)(lo + 8);
}

// MFMA GEMM C = Xh * Yh^T (K=1024) fused per-row packed-key top-3.
// 256x256 tile, 8 waves 2x4, 128x64 per wave (8x4 frags of 16x16x32 f16).
// BK=64, double-buffered, 1 barrier/K-tile, 1-ahead gload_lds staging.
__global__ __launch_bounds__(512, 2) void simKernel(
    const _Float16* __restrict__ Xh, const _Float16* __restrict__ Yh,
    float* __restrict__ pV1, unsigned* __restrict__ pK1,
    unsigned* __restrict__ pK2, unsigned* __restrict__ pK3) {
    __shared__ __align__(16) _Float16 As[2][256 * 64];   // 64 KB
    __shared__ __align__(16) _Float16 Bs[2][256 * 64];   // 64 KB
    __shared__ unsigned sK[2][4][128][3];                // 12 KB
    __shared__ float sE[2][4][128];                      //  4 KB -> 144 KB
    const int t = threadIdx.x;
    const int l = t & 63, w = t >> 6;        // 8 waves
    const int wr = w >> 2, wc = w & 3;       // 2 x 4 wave grid
    const int quad = l >> 4, lm = l & 15;
    // grid transpose: consecutive flat ids share the A row-tile
    const int flat = blockIdx.x;
    const int bx = flat >> 5, by = flat & 31;
    const int r0 = bx * 256, c0 = by * 256;

    f32x4 acc[8][4];
    #pragma unroll
    for (int i = 0; i < 8; i++)
        #pragma unroll
        for (int j = 0; j < 4; j++) acc[i][j] = (f32x4){0.f, 0.f, 0.f, 0.f};

    // --- staging geometry (global_load_lds, linear LDS dest) ---
    // Row-block rb in {0,64,128,192}: thread (w,l) stages 16B chunk
    // (row rb + w*8 + (l>>3), phys slot l&7) at LDS halves
    // rb*64 + w*512 + l*8 (HW lane scatter). Swizzle (both-sides):
    // phys slot p of row r holds logical k-slot p ^ (r&7); here r&7 = l>>3,
    // so the pre-swizzled global col = ((l&7) ^ (l>>3)) * 8.
    const int lh = l >> 3, ll = l & 7;
    const int srow = w * 8 + lh;                    // 0..63
    const int scol = (ll ^ lh) << 3;                // swizzled col (halves)
    const _Float16* gA0 = Xh + (size_t)(r0 + srow) * KY + scol;
    const _Float16* gB0 = Yh + (size_t)(c0 + srow) * KY + scol;
    const int ldsS = w * 512;                       // wave-uniform base (halves)

#define STAGE(bb, kt) do {                                                   \
    const size_t _ko = (size_t)(kt) * 64;                                    \
    gload16(gA0 + _ko,                       &As[bb][ldsS]);                 \
    gload16(gB0 + _ko,                       &Bs[bb][ldsS]);                 \
    gload16(gA0 + (size_t)64  * KY + _ko,    &As[bb][4096 + ldsS]);          \
    gload16(gB0 + (size_t)64  * KY + _ko,    &Bs[bb][4096 + ldsS]);          \
    gload16(gA0 + (size_t)128 * KY + _ko,    &As[bb][8192 + ldsS]);          \
    gload16(gB0 + (size_t)128 * KY + _ko,    &Bs[bb][8192 + ldsS]);          \
    gload16(gA0 + (size_t)192 * KY + _ko,    &As[bb][12288 + ldsS]);         \
    gload16(gB0 + (size_t)192 * KY + _ko,    &Bs[bb][12288 + ldsS]);         \
} while (0)

    // frag read addressing (halves): row*64 + ((ks*4+quad)^(lm&7))*8,
    // rows: A = wr*128 + i*16 + lm ; B = wc*64 + j*16 + lm (all bases %8==0)
    const int arow = (wr * 128 + lm) * 64;   // + i*1024
    const int brow = (wc * 64 + lm) * 64;    // + j*1024
    const int sw7 = lm & 7;

    // prologue: stage tile 0, drain, barrier
    STAGE(0, 0);
    asm volatile("s_waitcnt vmcnt(0)" ::: "memory");
    __builtin_amdgcn_s_barrier();
    __builtin_amdgcn_sched_barrier(0);

    #pragma unroll 1
    for (int kt = 0; kt < 16; kt++) {
        const int cur = kt & 1;
        // stage next K-tile into the other buffer (its readers finished at
        // the previous barrier); ~2500 cyc of compute covers the latency
        STAGE(cur ^ 1, (kt + 1) & 15);
        #pragma unroll
        for (int ks = 0; ks < 2; ks++) {
            const int cA = ((ks * 4 + quad) ^ sw7) << 3;
            v8h af[8], bf[4];
            #pragma unroll
            for (int i = 0; i < 8; i++)
                af[i] = *(const v8h*)&As[cur][arow + i * 1024 + cA];
            #pragma unroll
            for (int j = 0; j < 4; j++)
                bf[j] = *(const v8h*)&Bs[cur][brow + j * 1024 + cA];
            __builtin_amdgcn_s_setprio(1);
            #pragma unroll
            for (int j = 0; j < 4; j++)
                #pragma unroll
                for (int i = 0; i < 8; i++)
                    acc[i][j] = __builtin_amdgcn_mfma_f32_16x16x32_f16(af[i], bf[j], acc[i][j], 0, 0, 0);
            __builtin_amdgcn_s_setprio(0);
        }
        // next tile's 8 loads were issued ~2500 cyc ago -> near-free drain
        asm volatile("s_waitcnt vmcnt(0)" ::: "memory");
        __builtin_amdgcn_s_barrier();
        __builtin_amdgcn_sched_barrier(0);
    }
#undef STAGE

    // Epilogue: packed-key top-3 per row over this wave's 64 cols.
    // C frag layout: col=lane&15, row=quad*4+reg.
    const int cbase = c0 + wc * 64 + lm;
    #pragma unroll
    for (int i = 0; i < 8; i++) {
        #pragma unroll
        for (int r = 0; r < 4; r++) {
            float v0 = acc[i][0][r], v1 = acc[i][1][r];
            float v2 = acc[i][2][r], v3 = acc[i][3][r];
            unsigned k0 = packKey(v0, cbase);
            unsigned k1 = packKey(v1, cbase + 16);
            unsigned k2 = packKey(v2, cbase + 32);
            unsigned k3 = packKey(v3, cbase + 48);
            // local sorted top-3 of 4 (two sorted pairs -> order stats)
            unsigned h1 = umax(k0, k1), l1 = umin(k0, k1);
            unsigned h2 = umax(k2, k3), l2 = umin(k2, k3);
            unsigned a1 = umax(h1, h2);
            unsigned a2 = umax(umin(h1, h2), umax(l1, l2));
            unsigned a3 = umax(umin(h1, l2), umin(l1, h2));
            float ev = fmaxf(fmaxf(v0, v1), fmaxf(v2, v3));
            #pragma unroll
            for (int m = 1; m < 16; m <<= 1) {
                unsigned b1 = (unsigned)__shfl_xor((int)a1, m, 64);
                unsigned b2 = (unsigned)__shfl_xor((int)a2, m, 64);
                unsigned b3 = (unsigned)__shfl_xor((int)a3, m, 64);
                float be = __shfl_xor(ev, m, 64);
                KMERGE(a1, a2, a3, b1, b2, b3);
                ev = fmaxf(ev, be);
            }
            if (lm == 0) {
                int rr = i * 16 + quad * 4 + r;   // 0..127 within wave rows
                sK[wr][wc][rr][0] = a1; sK[wr][wc][rr][1] = a2; sK[wr][wc][rr][2] = a3;
                sE[wr][wc][rr] = ev;
            }
        }
    }
    __syncthreads();
    // merge 4 wave-columns; threads 0..255 each own one of the 256 rows
    if (t < 256) {
        const int mwr = t >> 7, ri = t & 127;
        unsigned a1 = sK[mwr][0][ri][0], a2 = sK[mwr][0][ri][1], a3 = sK[mwr][0][ri][2];
        float ev = sE[mwr][0][ri];
        #pragma unroll
        for (int q = 1; q < 4; q++) {
            unsigned b1 = sK[mwr][q][ri][0], b2 = sK[mwr][q][ri][1], b3 = sK[mwr][q][ri][2];
            KMERGE(a1, a2, a3, b1, b2, b3);
            ev = fmaxf(ev, sE[mwr][q][ri]);
        }
        size_t o = (size_t)by * NROWS + (r0 + t);
        pV1[o] = ev;
        pK1[o] = a1; pK2[o] = a2; pK3[o] = a3;
    }
}

// 128 blocks, 4 threads per row, 8 chunks each; shuffle-merge across sub.
__global__ __launch_bounds__(256) void reduceKernel(
    const float* __restrict__ pV1, const unsigned* __restrict__ pK1,
    const unsigned* __restrict__ pK2, const unsigned* __restrict__ pK3,
    int* __restrict__ bestIdx, int* __restrict__ flagRows,
    int* __restrict__ flagC2, int* __restrict__ flagC3,
    int* __restrict__ flagCnt, float* __restrict__ blkSum) {
    int t = threadIdx.x;
    int g = blockIdx.x * 256 + t;
    int row = g >> 2, sub = g & 3;
    unsigned a1 = 0, a2 = 0, a3 = 0;
    float ev = -1e30f;
    #pragma unroll
    for (int k = 0; k < 8; k++) {
        size_t o = (size_t)(sub + (k << 2)) * NROWS + row;
        unsigned b1 = pK1[o], b2 = pK2[o], b3 = pK3[o];
        float e = pV1[o];
        KMERGE(a1, a2, a3, b1, b2, b3);
        ev = fmaxf(ev, e);
    }
    #pragma unroll
    for (int m = 1; m < 4; m <<= 1) {
        unsigned b1 = (unsigned)__shfl_xor((int)a1, m, 64);
        unsigned b2 = (unsigned)__shfl_xor((int)a2, m, 64);
        unsigned b3 = (unsigned)__shfl_xor((int)a3, m, 64);
        float be = __shfl_xor(ev, m, 64);
        KMERGE(a1, a2, a3, b1, b2, b3);
        ev = fmaxf(ev, be);
    }
    bool lead = (t & 3) == 0;
    if (lead) {
        bestIdx[row] = 8191 - (int)(a1 & 8191u);
        // flag if exact max minus lower-bound of 2nd key is within margin
        if (ev - unpackApprox(a2) < FEPS) {
            int s = atomicAdd(flagCnt, 1);
            flagRows[s] = row;
            flagC2[s] = 8191 - (int)(a2 & 8191u);
            flagC3[s] = 8191 - (int)(a3 & 8191u);
        }
    }
    double sum = lead ? 1.0 - (double)ev : 0.0;
    __shared__ double sh[4];
    #pragma unroll
    for (int off = 32; off; off >>= 1) sum += __shfl_down(sum, off, 64);
    if ((t & 63) == 0) sh[t >> 6] = sum;
    __syncthreads();
    if (t == 0) blkSum[blockIdx.x] = (float)(sh[0] + sh[1] + sh[2] + sh[3]);
}

// Exact fp64 re-check of top-3 candidates for near-tie rows; one wave per row.
__global__ __launch_bounds__(256) void refineKernel(
    const _Float16* __restrict__ Xh, const _Float16* __restrict__ Xl,
    const _Float16* __restrict__ Yh, const _Float16* __restrict__ Yl,
    int* __restrict__ bestIdx, const int* __restrict__ flagRows,
    const int* __restrict__ flagC2, const int* __restrict__ flagC3,
    const int* __restrict__ flagCnt) {
    int n = *flagCnt;
    int wave = (blockIdx.x << 2) + (threadIdx.x >> 6);
    int ln = threadIdx.x & 63;
    for (int fi = wave; fi < n; fi += gridDim.x * 4) {
        int row = flagRows[fi];
        int cand[3];
        cand[0] = bestIdx[row]; cand[1] = flagC2[fi]; cand[2] = flagC3[fi];
        double d[3];
        #pragma unroll
        for (int c = 0; c < 3; c++) {
            double p = 0.0;
            int yr = cand[c];
            #pragma unroll
            for (int q = 0; q < 16; q++) {
                int k = (ln << 4) + q;
                float xv = (float)Xh[(size_t)row * KY + k] + (float)Xl[(size_t)row * KY + k];
                float yv = (float)Yh[(size_t)yr * KY + k] + (float)Yl[(size_t)yr * KY + k];
                p += (double)xv * yv;
            }
            #pragma unroll
            for (int m = 1; m < 64; m <<= 1) p += __shfl_xor(p, m, 64);
            d[c] = p;
        }
        if (ln == 0) {
            int bi = cand[0]; double bv = d[0];
            #pragma unroll
            for (int c = 1; c < 3; c++) {
                if (d[c] > bv || (d[c] == bv && cand[c] < bi)) { bv = d[c]; bi = cand[c]; }
            }
            bestIdx[row] = bi;
        }
    }
}

// new_x gather (hi+lo reconstruct ~ fp32 codebook) + loss finalize.
__global__ __launch_bounds__(256) void gatherKernel(
    const _Float16* __restrict__ Yh, const _Float16* __restrict__ Yl,
    const int* __restrict__ bestIdx, const float* __restrict__ blkSum,
    float* __restrict__ out) {
    int t = threadIdx.x;
    if (blockIdx.x == 0 && t == 0) {
        double s = 0.0;
        for (int i = 0; i < 128; i++) s += (double)blkSum[i];
        out[0] = (float)(s / 8192.0);
    }
    int g = (blockIdx.x * 256 + t) << 2;
    int b = g >> 20, wq = (g >> 13) & 127, hq = (g >> 6) & 127, d = g & 63;
    int row = (b << 10) + ((wq >> 2) << 5) + (hq >> 2);
    int f = ((wq & 3) << 8) + ((hq & 3) << 6) + d;
    size_t base = (size_t)bestIdx[row] * KY + f;
    const _Float16* ph = &Yh[base];
    const _Float16* pl = &Yl[base];
    out[1 + g + 0] = (float)ph[0] + (float)pl[0];
    out[1 + g + 1] = (float)ph[1] + (float)pl[1];
    out[1 + g + 2] = (float)ph[2] + (float)pl[2];
    out[1 + g + 3] = (float)ph[3] + (float)pl[3];
}

extern "C" void kernel_launch(void* const* d_in, const int* in_sizes, int n_in,
                              void* d_out, int out_size, void* d_ws, size_t ws_size,
                              hipStream_t stream) {
    const float* x = (const float*)d_in[0];
    const float* y = (const float*)d_in[1];
    float* out = (float*)d_out;
    char* ws = (char*)d_ws;
    _Float16* Xh  = (_Float16*)(ws);
    _Float16* Xl  = (_Float16*)(ws + 16777216u);
    _Float16* Yh  = (_Float16*)(ws + 33554432u);
    _Float16* Yl  = (_Float16*)(ws + 50331648u);
    float* pV1    = (float*)(ws + 67108864u);
    unsigned* pK1 = (unsigned*)(ws + 69206016u);
    unsigned* pK2 = (unsigned*)(ws + 71303168u);
    unsigned* pK3 = (unsigned*)(ws + 73400320u);
    int* bestIdx  = (int*)  (ws + 79691776u);
    int* flagRows = (int*)  (ws + 79724544u);
    int* flagC2   = (int*)  (ws + 79757312u);
    int* flagC3   = (int*)  (ws + 79790080u);
    int* flagCnt  = (int*)  (ws + 79822848u);
    float* blkSum = (float*)(ws + 79822976u);

    normSplitKernel<<<4096, 256, 0, stream>>>(x, y, Xh, Xl, Yh, Yl, flagCnt);
    simKernel<<<1024, 512, 0, stream>>>(Xh, Yh, pV1, pK1, pK2, pK3);
    reduceKernel<<<128, 256, 0, stream>>>(pV1, pK1, pK2, pK3,
                                          bestIdx, flagRows, flagC2, flagC3, flagCnt, blkSum);
    refineKernel<<<64, 256, 0, stream>>>(Xh, Xl, Yh, Yl, bestIdx,
                                         flagRows, flagC2, flagC3, flagCnt);
    gatherKernel<<<8192, 256, 0, stream>>>(Yh, Yl, bestIdx, blkSum, out);
}